// Round 1
// baseline (332.636 us; speedup 1.0000x reference)
//
#include <hip/hip_runtime.h>
#include <stdint.h>

#define S_LEN 4096
#define DHEAD 256
#define NTILES (S_LEN / 64)

typedef __attribute__((ext_vector_type(8))) __bf16 bf16x8;
typedef __attribute__((ext_vector_type(8))) short short8;
typedef __attribute__((ext_vector_type(4))) float f32x4;

__device__ __forceinline__ short f2bf_rn(float f) {
    uint32_t u = __builtin_bit_cast(uint32_t, f);
    u += 0x7FFFu + ((u >> 16) & 1u);
    return (short)(u >> 16);
}

template<bool B16>
__device__ __forceinline__ short8 ld8s(const void* base, size_t off) {
    if constexpr (B16) {
        return *reinterpret_cast<const short8*>(reinterpret_cast<const short*>(base) + off);
    } else {
        const float* p = reinterpret_cast<const float*>(base) + off;
        float4 a = *reinterpret_cast<const float4*>(p);
        float4 b = *reinterpret_cast<const float4*>(p + 4);
        short8 r;
        r[0] = f2bf_rn(a.x); r[1] = f2bf_rn(a.y); r[2] = f2bf_rn(a.z); r[3] = f2bf_rn(a.w);
        r[4] = f2bf_rn(b.x); r[5] = f2bf_rn(b.y); r[6] = f2bf_rn(b.z); r[7] = f2bf_rn(b.w);
        return r;
    }
}

__global__ void cvt_bf16(const float* __restrict__ src, short* __restrict__ dst, int n) {
    int i = (blockIdx.x * blockDim.x + threadIdx.x) * 8;
    if (i >= n) return;
    short8 r = ld8s<false>(src, (size_t)i);
    *reinterpret_cast<short8*>(dst + i) = r;
}

__global__ void combine(float* __restrict__ out, const float* __restrict__ part, int n) {
    int i = (blockIdx.x * blockDim.x + threadIdx.x) * 4;
    if (i >= n) return;
    float4 a = *reinterpret_cast<float4*>(out + i);
    float4 b = *reinterpret_cast<const float4*>(part + i);
    a.x += b.x; a.y += b.y; a.z += b.z; a.w += b.w;
    *reinterpret_cast<float4*>(out + i) = a;
}

// Flash attention pass. pass = passBase + (blockIdx.x>>8).
//   pass 0: Q=K=h_p, V=h_b, dst=out, adds residual (h_b+h_p, fp32)
//   pass 1: Q=K=h_b, V=h_p, dst=part (or accumulates into out if accum=1)
// Block: 256 threads = 4 waves; block q-tile = 64 rows, wave = 16 rows; KV tile = 64.
template<bool B16>
__global__ __launch_bounds__(256, 2) void attn_main(
    const void* __restrict__ hbS, const void* __restrict__ hpS,
    const float* __restrict__ hb32, const float* __restrict__ hp32,
    float* __restrict__ out, float* __restrict__ part,
    int passBase, int accum)
{
    // K: row-major [kv][d], pad 256->264 so b128 reads across rows hit different banks
    __shared__ __align__(16) short Klds[64][264];
    // V transposed: [d][kv], pad 64->72 (row stride 144B -> 2-way aliasing only)
    __shared__ __align__(16) short Vt[256][72];
    // P scratch per wave: [q][kv], pad 64->72
    __shared__ __align__(16) short Plds[4][16][72];

    const int bid = blockIdx.x;
    const int pass = passBase + (bid >> 8);
    const int bt = bid & 255;
    const int batch = bt >> 6;
    const int q0 = (bt & 63) * 64;
    const size_t off = (size_t)batch * S_LEN * DHEAD;

    const void* qk = pass ? hbS : hpS;
    const void* vv = pass ? hpS : hbS;

    const int tid = threadIdx.x;
    const int w = tid >> 6, lane = tid & 63;
    const int lhi = lane >> 4, llo = lane & 15;

    // Q fragments, hoisted: lane holds Q[q0+w*16+llo][kc*32 + 8*lhi + j], j=0..7
    bf16x8 qf[8];
    {
        size_t qoff = off + (size_t)(q0 + w * 16 + llo) * DHEAD + 8 * lhi;
        #pragma unroll
        for (int kc = 0; kc < 8; ++kc)
            qf[kc] = __builtin_bit_cast(bf16x8, ld8s<B16>(qk, qoff + kc * 32));
    }

    f32x4 acc[16];
    #pragma unroll
    for (int i = 0; i < 16; ++i) acc[i] = (f32x4){0.f, 0.f, 0.f, 0.f};
    float mrun[4] = {-1e30f, -1e30f, -1e30f, -1e30f};
    float lrun[4] = {0.f, 0.f, 0.f, 0.f};

    // V staging map: thread owns kv column (t&63), d-range (t>>6)*64..+63
    const int vkv = tid & 63;
    const int vdb = (tid >> 6) * 64;

    for (int kt = 0; kt < NTILES; ++kt) {
        const int kv0 = kt * 64;
        __syncthreads();
        // K tile: linear coalesced copy
        #pragma unroll
        for (int r = 0; r < 8; ++r) {
            int idx = r * 2048 + tid * 8;
            int kv = idx >> 8, d0 = idx & 255;
            short8 x = ld8s<B16>(qk, off + (size_t)(kv0 + kv) * DHEAD + d0);
            *reinterpret_cast<short8*>(&Klds[kv][d0]) = x;
        }
        // V tile: transpose into Vt (writes land 2 lanes/bank = free)
        {
            size_t vo = off + (size_t)(kv0 + vkv) * DHEAD + vdb;
            #pragma unroll
            for (int r = 0; r < 8; ++r) {
                short8 x = ld8s<B16>(vv, vo + r * 8);
                #pragma unroll
                for (int i = 0; i < 8; ++i) Vt[vdb + r * 8 + i][vkv] = x[i];
            }
        }
        __syncthreads();

        // QK^T: S[q][kv] for 4 kv16 blocks. C/D: col=llo (kv), row=lhi*4+reg (q)
        float sv[4][4];
        #pragma unroll
        for (int tt = 0; tt < 4; ++tt) {
            f32x4 s = (f32x4){0.f, 0.f, 0.f, 0.f};
            const short* kb = &Klds[tt * 16 + llo][8 * lhi];
            #pragma unroll
            for (int kc = 0; kc < 8; ++kc) {
                bf16x8 kf = *reinterpret_cast<const bf16x8*>(kb + kc * 32);
                s = __builtin_amdgcn_mfma_f32_16x16x32_bf16(qf[kc], kf, s, 0, 0, 0);
            }
            #pragma unroll
            for (int r = 0; r < 4; ++r) sv[tt][r] = s[r];
        }

        // online softmax per q-row (reg r); kv spread over 4 tt's and 16 lanes (llo)
        #pragma unroll
        for (int r = 0; r < 4; ++r) {
            float tm = fmaxf(fmaxf(sv[0][r], sv[1][r]), fmaxf(sv[2][r], sv[3][r]));
            tm = fmaxf(tm, __shfl_xor(tm, 1));
            tm = fmaxf(tm, __shfl_xor(tm, 2));
            tm = fmaxf(tm, __shfl_xor(tm, 4));
            tm = fmaxf(tm, __shfl_xor(tm, 8));
            float mn = fmaxf(mrun[r], tm);
            float al = __expf(mrun[r] - mn);
            mrun[r] = mn;
            float ps = 0.f;
            #pragma unroll
            for (int tt = 0; tt < 4; ++tt) {
                float p = __expf(sv[tt][r] - mn);
                sv[tt][r] = p;
                ps += p;
            }
            ps += __shfl_xor(ps, 1);
            ps += __shfl_xor(ps, 2);
            ps += __shfl_xor(ps, 4);
            ps += __shfl_xor(ps, 8);
            lrun[r] = lrun[r] * al + ps;
            #pragma unroll
            for (int db = 0; db < 16; ++db) acc[db][r] *= al;
            #pragma unroll
            for (int tt = 0; tt < 4; ++tt)
                Plds[w][lhi * 4 + r][llo + 16 * tt] = f2bf_rn(sv[tt][r]);
        }
        asm volatile("s_waitcnt lgkmcnt(0)" ::: "memory");

        // PV: out[q][d] += P[q][kv] V[kv][d]; A=P from Plds, B=V from Vt (both contiguous-k)
        #pragma unroll
        for (int kc = 0; kc < 2; ++kc) {
            bf16x8 pf = *reinterpret_cast<const bf16x8*>(&Plds[w][llo][kc * 32 + 8 * lhi]);
            #pragma unroll
            for (int db = 0; db < 16; ++db) {
                bf16x8 vf = *reinterpret_cast<const bf16x8*>(&Vt[db * 16 + llo][kc * 32 + 8 * lhi]);
                acc[db] = __builtin_amdgcn_mfma_f32_16x16x32_bf16(pf, vf, acc[db], 0, 0, 0);
            }
        }
    }

    float inv[4];
    #pragma unroll
    for (int r = 0; r < 4; ++r) inv[r] = 1.f / lrun[r];

    float* dst = (pass == 0 || accum) ? out : part;
    #pragma unroll
    for (int db = 0; db < 16; ++db) {
        #pragma unroll
        for (int r = 0; r < 4; ++r) {
            int q = q0 + w * 16 + lhi * 4 + r;
            int d = db * 16 + llo;
            size_t o = off + (size_t)q * DHEAD + d;
            float v = acc[db][r] * inv[r];
            if (pass == 0) v += hb32[o] + hp32[o];
            else if (accum) v += dst[o];
            dst[o] = v;
        }
    }
}

extern "C" void kernel_launch(void* const* d_in, const int* in_sizes, int n_in,
                              void* d_out, int out_size, void* d_ws, size_t ws_size,
                              hipStream_t stream) {
    const float* hb = (const float*)d_in[0];
    const float* hp = (const float*)d_in[1];
    float* out = (float*)d_out;
    const int n = 4 * S_LEN * DHEAD;  // 4,194,304 elements per tensor
    const size_t need = (size_t)n * 2 * 2 + (size_t)n * 4;  // 2x bf16 copies + fp32 partial = 32MB
    if (ws_size >= need) {
        short* hb16 = (short*)d_ws;
        short* hp16 = hb16 + n;
        float* part = (float*)(hp16 + n);
        cvt_bf16<<<n / 2048, 256, 0, stream>>>(hb, hb16, n);
        cvt_bf16<<<n / 2048, 256, 0, stream>>>(hp, hp16, n);
        attn_main<true><<<512, 256, 0, stream>>>(hb16, hp16, hb, hp, out, part, 0, 0);
        combine<<<n / 1024, 256, 0, stream>>>(out, part, n);
    } else {
        // fallback: no ws — fp32-source staging, two sequential launches accumulate into out
        attn_main<false><<<256, 256, 0, stream>>>(hb, hp, hb, hp, out, nullptr, 0, 0);
        attn_main<false><<<256, 256, 0, stream>>>(hb, hp, hb, hp, out, nullptr, 1, 1);
    }
}